// Round 10
// baseline (352.151 us; speedup 1.0000x reference)
//
#include <hip/hip_runtime.h>
#include <hip/hip_bf16.h>
#include <math.h>

// Problem constants (QwenAttention: B=2,S=2048,E=2048,H=16,KV=4,D=128)
#define BB 2
#define SS 2048
#define EE 2048
#define HH 16
#define KVH 4
#define DD 128
#define QTILES 32   // S / 64

typedef short short8 __attribute__((ext_vector_type(8)));
typedef float f32x4 __attribute__((ext_vector_type(4)));

__device__ __forceinline__ unsigned int f2bf1(float x) {
    union { float f; unsigned int u; } v; v.f = x;
    return (v.u + 0x7FFFu + ((v.u >> 16) & 1u)) >> 16;  // RNE bf16
}
__device__ __forceinline__ unsigned int packbf(float a, float b) {
    return f2bf1(a) | (f2bf1(b) << 16);
}
// async global->LDS, 16B per lane; LDS dest = wave-uniform base + lane*16
__device__ __forceinline__ void gl_lds16(const void* g, void* l) {
    __builtin_amdgcn_global_load_lds(
        (const __attribute__((address_space(1))) unsigned int*)g,
        (__attribute__((address_space(3))) unsigned int*)l,
        16, 0, 0);
}

// ---------------------------------------------------------------------------
// Fused fp32->bf16 conversion of all inputs + bias concat + RoPE cos/sin
// table, one launch. Segments in float4 units: x | Wq | Wk | Wv | Wo |
// biases(fp32) | rope table (cos[2048][64], sin[2048][64] f32).
// ---------------------------------------------------------------------------
__global__ __launch_bounds__(256) void cvt_all_kernel(
    const float* __restrict__ x,  const float* __restrict__ Wq,
    const float* __restrict__ Wk, const float* __restrict__ Wv,
    const float* __restrict__ Wo, const float* __restrict__ bq,
    const float* __restrict__ bk, const float* __restrict__ bv,
    unsigned short* __restrict__ xb, unsigned short* __restrict__ wqkv,
    unsigned short* __restrict__ wob, float* __restrict__ bqkv,
    float* __restrict__ rtab)
{
    long id = (long)blockIdx.x * 256 + threadIdx.x;
    const float* src; unsigned short* dst; long j;
    if (id < 2097152)      { j = id;           src = x;  dst = xb; }
    else if (id < 3145728) { j = id - 2097152; src = Wq; dst = wqkv; }
    else if (id < 3407872) { j = id - 3145728; src = Wk; dst = wqkv + 4194304; }
    else if (id < 3670016) { j = id - 3407872; src = Wv; dst = wqkv + 5242880; }
    else if (id < 4718592) { j = id - 3670016; src = Wo; dst = wob; }
    else if (id < 4719360) {
        long c = (id - 4718592) * 4;
#pragma unroll
        for (int e = 0; e < 4; ++e) {
            long cc = c + e;
            bqkv[cc] = (cc < 2048) ? bq[cc] : (cc < 2560 ? bk[cc - 2048] : bv[cc - 2560]);
        }
        return;
    } else if (id < 4850432) {
        // rope table: one sincos per (s, d) entry
        long e = id - 4719360;            // 0 .. 131071
        int sg = (int)(e >> 6);           // position 0..2047
        int dg = (int)(e & 63);           // freq index 0..63
        float inv_freq = expf(-(float)dg * (logf(10000.0f) / 64.0f));
        float fr = (float)sg * inv_freq;
        rtab[e]          = cosf(fr);
        rtab[131072 + e] = sinf(fr);
        return;
    } else return;
    float4 f = ((const float4*)src)[j];
    ((uint2*)dst)[j] = make_uint2(packbf(f.x, f.y), packbf(f.z, f.w));
}

// ---------------------------------------------------------------------------
// bf16 MFMA GEMM: C[M,N] = A[M,K] @ W[N,K]^T + bias[N]
// 128x128 tile, BK=64, 256 threads = 4 waves (2x2), 4x4 MFMA tiles per wave.
// r9: BK=64 + XOR-swizzled LDS (pre-swizzled global src col
// ((lane&7)^(lane>>3))*8, read chunk' = chunk ^ (row&7)) -> min bank rounds.
// THIS round: T3 minimal 2-phase. Double-buffered LDS tiles; issue tile
// t+1's global_load_lds BEFORE computing tile t; ONE __syncthreads per step
// (its implicit vmcnt(0) drain lands after the loads had the whole MFMA
// phase in flight). Barriers/step 2 -> 1; staging overlaps compute.
// Hazards: buf^1 writes at t vs buf^1 reads at t-1 separated by t-1's
// barrier; compute of buf at t covered by same barrier's vmcnt(0) drain.
// (r7 lesson: keep the epilogue simple -- no fused rope.)
// ---------------------------------------------------------------------------
template <bool OUT_BF16>
__global__ __launch_bounds__(256) void gemm_mfma_kernel(
    const unsigned short* __restrict__ A, const unsigned short* __restrict__ W,
    const float* __restrict__ bias, void* __restrict__ Cout,
    int M, int N, int K)
{
    __shared__ unsigned short As[2][128 * 64];   // 2 x 16 KB
    __shared__ unsigned short Bs[2][128 * 64];   // 2 x 16 KB

    const int tid  = threadIdx.x;
    const int w    = tid >> 6;
    const int lane = tid & 63;
    const int quad = lane >> 4;
    const int l16  = lane & 15;
    const int wr   = w >> 1, wc = w & 1;
    const int m0 = blockIdx.y * 128, n0 = blockIdx.x * 128;

    f32x4 acc[4][4];
#pragma unroll
    for (int i = 0; i < 4; ++i)
#pragma unroll
        for (int j = 0; j < 4; ++j) acc[i][j] = (f32x4){0.f, 0.f, 0.f, 0.f};

    // staging map: dest LDS row (within 32-row call-chunk) = w*8 + (lane>>3),
    // dest chunk = lane&7; source col pre-swizzled so LDS logical layout is
    // row-major with chunk' = chunk ^ (row&7); row&7 == lane>>3.
    const int scol = ((lane & 7) ^ (lane >> 3)) * 8;
    const unsigned short* Ag = A + (size_t)(m0 + w * 8 + (lane >> 3)) * K + scol;
    const unsigned short* Wg = W + (size_t)(n0 + w * 8 + (lane >> 3)) * K + scol;

    const int rkey = (l16 & 7) * 8;   // read-side XOR key (in shorts)
    const int nt = K >> 6;

    // ---- prologue: stage tile 0 into buffer 0 ----
#pragma unroll
    for (int c = 0; c < 4; ++c) {
        gl_lds16(Ag + (size_t)(32 * c) * K, &As[0][(w * 8 + 32 * c) * 64]);
        gl_lds16(Wg + (size_t)(32 * c) * K, &Bs[0][(w * 8 + 32 * c) * 64]);
    }
    __syncthreads();

    int cur = 0;
    for (int t = 0; t < nt; ++t) {
        // ---- issue next-tile loads into the other buffer (async) ----
        if (t + 1 < nt) {
            const size_t k0 = (size_t)(t + 1) << 6;
#pragma unroll
            for (int c = 0; c < 4; ++c) {
                gl_lds16(Ag + k0 + (size_t)(32 * c) * K, &As[cur ^ 1][(w * 8 + 32 * c) * 64]);
                gl_lds16(Wg + k0 + (size_t)(32 * c) * K, &Bs[cur ^ 1][(w * 8 + 32 * c) * 64]);
            }
        }
        // ---- compute current buffer ----
        const unsigned short* Asr = As[cur];
        const unsigned short* Bsr = Bs[cur];
#pragma unroll
        for (int ks = 0; ks < 2; ++ks) {
            short8 a_f[4], b_f[4];
#pragma unroll
            for (int i = 0; i < 4; ++i)
                a_f[i] = *(const short8*)&Asr[(wr * 64 + i * 16 + l16) * 64 + (((ks * 4 + quad) * 8) ^ rkey)];
#pragma unroll
            for (int j = 0; j < 4; ++j)
                b_f[j] = *(const short8*)&Bsr[(wc * 64 + j * 16 + l16) * 64 + (((ks * 4 + quad) * 8) ^ rkey)];
#pragma unroll
            for (int i = 0; i < 4; ++i)
#pragma unroll
                for (int j = 0; j < 4; ++j)
                    acc[i][j] = __builtin_amdgcn_mfma_f32_16x16x32_bf16(a_f[i], b_f[j], acc[i][j], 0, 0, 0);
        }
        // ---- one barrier per step: drains next-tile loads (which flew
        //      under the MFMA phase) and fences buffer reuse ----
        __syncthreads();
        cur ^= 1;
    }

    float bj[4];
#pragma unroll
    for (int j = 0; j < 4; ++j)
        bj[j] = bias ? bias[n0 + wc * 64 + j * 16 + l16] : 0.0f;
#pragma unroll
    for (int i = 0; i < 4; ++i) {
#pragma unroll
        for (int r = 0; r < 4; ++r) {
            size_t row = m0 + wr * 64 + i * 16 + quad * 4 + r;
#pragma unroll
            for (int j = 0; j < 4; ++j) {
                size_t col = n0 + wc * 64 + j * 16 + l16;
                float val = acc[i][j][r] + bj[j];
                if (OUT_BF16)
                    ((unsigned short*)Cout)[row * N + col] = (unsigned short)f2bf1(val);
                else
                    ((float*)Cout)[row * N + col] = val;
            }
        }
    }
}

// ---------------------------------------------------------------------------
// RoPE on bf16 qkv buffer [M, 3072] (q cols 0..2047, k cols 2048..2559).
// Table-based: cos/sin from precomputed [2048][64] f32 tables (no device
// trig in hot path). One block per row, 256 threads x 5 pairs.
// ---------------------------------------------------------------------------
__global__ __launch_bounds__(256) void rope_kernel(
    unsigned short* __restrict__ qkv,
    const float* __restrict__ ctab, const float* __restrict__ stab)
{
    const int m = blockIdx.x;          // row in [0, B*S)
    const int s = m & (SS - 1);
    unsigned short* p = qkv + (size_t)m * 3072;
    const float* cr = ctab + s * 64;
    const float* sr = stab + s * 64;
#pragma unroll
    for (int it = 0; it < 5; ++it) {
        int idx = threadIdx.x + it * 256;   // 0..1279 : 20 heads x 64 pairs
        int hh = idx >> 6;
        int d  = idx & 63;
        int cb = (hh < 16) ? hh * 128 : 2048 + (hh - 16) * 128;
        float c  = cr[d];
        float sn = sr[d];
        union { unsigned int u; float f; } x1, x2;
        x1.u = ((unsigned int)p[cb + d]) << 16;
        x2.u = ((unsigned int)p[cb + d + 64]) << 16;
        p[cb + d]      = (unsigned short)f2bf1(x1.f * c - x2.f * sn);
        p[cb + d + 64] = (unsigned short)f2bf1(x2.f * c + x1.f * sn);
    }
}

// ---------------------------------------------------------------------------
// Flash attention, bf16, MFMA 16x16x32, XOR-swizzled LDS (conflict-free),
// double-buffered K/V with register prefetch -> ONE barrier per K-tile.
// 512 blocks, each does TWO q-tiles (jpair, 31-jpair) = uniform 33 KV-units.
// Structure locked by rounds 1/2/4/6/8 (all null or regressed): keep dbuf +
// (256,2); no split-KV, no XCD swizzle, no setprio, no defer-rescale; the
// batched softmax trees (r8) are kept (neutral, no cost).
// qkv: [B*S, 3072] (q: h*128, k: 2048+kv*128, v: 2560+kv*128); o: [B*S, 2048].
// Swizzle keys: K/V chunk' = chunk ^ ((row + (row>>4)) & 7) at 16B-chunk
// granularity; P chunk' = chunk ^ ((row>>2) ^ ((row&3)<<1)).
// ---------------------------------------------------------------------------
__global__ __launch_bounds__(256, 2) void attn_mfma_kernel(
    const unsigned short* __restrict__ qkv, unsigned short* __restrict__ o)
{
    __shared__ unsigned int Ks_u[2][64 * 64];    // 2 x 16 KB
    __shared__ unsigned int Vs_u[2][128 * 32];   // 2 x 16 KB
    __shared__ unsigned short Ps[4][16 * 64];    // 8 KB, per-wave

    const int tid  = threadIdx.x;
    const int w    = tid >> 6;
    const int lane = tid & 63;
    const int quad = lane >> 4;
    const int l16  = lane & 15;
    const int jpair = blockIdx.x;   // 0..15
    const int h     = blockIdx.y;
    const int b     = blockIdx.z;
    const int kv    = h >> 2;       // G = 4

    const float k2 = 0.12752789744920764f;  // (1/sqrt(128)) * log2(e)

    const unsigned short* kbase = qkv + (size_t)b * SS * 3072 + 2048 + kv * 128;
    const unsigned short* vbase = kbase + 512;

    const int kc  = tid & 15;          // K chunk (8 dims)
    const int kp0 = tid >> 4;          // K row base 0..15
    const int vpp = tid >> 3;          // V pos-pair 0..31
    const int vd0 = (tid & 7) * 16;    // V d-segment base

    for (int pass = 0; pass < 2; ++pass) {
        const int qt = pass ? (QTILES - 1 - jpair) : jpair;
        const int q0 = qt * 64;

        // ---- Q A-frags ----
        short8 qf[4];
        {
            const unsigned short* qp = qkv + (size_t)(b * SS + q0 + w * 16 + l16) * 3072 + h * 128 + quad * 8;
#pragma unroll
            for (int ks = 0; ks < 4; ++ks)
                qf[ks] = *(const short8*)(qp + ks * 32);
        }

        // ---- prefetch tile 0 into regs ----
        uint4 kpre[4], vpa[2], vpb[2];
        {
            const unsigned short* kg = kbase + (size_t)kp0 * 3072 + kc * 8;
#pragma unroll
            for (int rr = 0; rr < 4; ++rr)
                kpre[rr] = *(const uint4*)(kg + (size_t)rr * 16 * 3072);
            const unsigned short* vg = vbase + (size_t)(2 * vpp) * 3072 + vd0;
            vpa[0] = *(const uint4*)(vg);
            vpa[1] = *(const uint4*)(vg + 8);
            vpb[0] = *(const uint4*)(vg + 3072);
            vpb[1] = *(const uint4*)(vg + 3072 + 8);
        }

        float m_r[4], l_r[4];
        f32x4 Oacc[8];
#pragma unroll
        for (int r = 0; r < 4; ++r) { m_r[r] = -1e30f; l_r[r] = 0.0f; }
#pragma unroll
        for (int ot = 0; ot < 8; ++ot) Oacc[ot] = (f32x4){0.f, 0.f, 0.f, 0.f};

        for (int t = 0; t <= qt; ++t) {
            const int buf = t & 1;
            unsigned int* Kb = Ks_u[buf];
            unsigned int* Vb = Vs_u[buf];

            // ---- staged regs -> LDS (swizzled, conflict-free) ----
#pragma unroll
            for (int rr = 0; rr < 4; ++rr) {
                int pos = kp0 + rr * 16;
                int key = (kp0 + rr) & 7;           // (pos + (pos>>4)) & 7
                *(uint4*)&Kb[pos * 64 + (kc ^ key) * 4] = kpre[rr];
            }
            {
                const unsigned int* pa = (const unsigned int*)vpa;
                const unsigned int* pb = (const unsigned int*)vpb;
#pragma unroll
                for (int j = 0; j < 8; ++j) {
                    unsigned lo = __builtin_amdgcn_perm(pb[j], pa[j], 0x05040100);
                    unsigned hi = __builtin_amdgcn_perm(pb[j], pa[j], 0x07060302);
                    int d0 = vd0 + 2 * j;
                    int g  = d0 >> 4;               // same for d0 and d0+1
                    int k0 = (d0 + g) & 7;
                    int k1 = (d0 + 1 + g) & 7;
                    Vb[d0 * 32 + (((vpp >> 2) ^ k0) & 7) * 4 + (vpp & 3)] = lo;
                    Vb[(d0 + 1) * 32 + (((vpp >> 2) ^ k1) & 7) * 4 + (vpp & 3)] = hi;
                }
            }

            // ---- prefetch tile t+1 (latency hidden under compute) ----
            if (t < qt) {
                const unsigned short* kg = kbase + (size_t)((t + 1) * 64 + kp0) * 3072 + kc * 8;
#pragma unroll
                for (int rr = 0; rr < 4; ++rr)
                    kpre[rr] = *(const uint4*)(kg + (size_t)rr * 16 * 3072);
                const unsigned short* vg = vbase + (size_t)((t + 1) * 64 + 2 * vpp) * 3072 + vd0;
                vpa[0] = *(const uint4*)(vg);
                vpa[1] = *(const uint4*)(vg + 8);
                vpb[0] = *(const uint4*)(vg + 3072);
                vpb[1] = *(const uint4*)(vg + 3072 + 8);
            }
            __syncthreads();

            // ---- S = Q @ K^T (16x64 per wave), raw scores ----
            f32x4 S[4];
#pragma unroll
            for (int ct = 0; ct < 4; ++ct) {
                f32x4 s = (f32x4){0.f, 0.f, 0.f, 0.f};
                const int row = ct * 16 + l16;
                const int key = (l16 + ct) & 7;     // (pos + (pos>>4)) & 7
#pragma unroll
                for (int ks = 0; ks < 4; ++ks) {
                    short8 kf = *(const short8*)&Kb[row * 64 + ((ks * 4 + quad) ^ key) * 4];
                    s = __builtin_amdgcn_mfma_f32_16x16x32_bf16(qf[ks], kf, s, 0, 0, 0);
                }
                S[ct] = s;
            }

            // ---- causal mask (diagonal tile only) ----
            if (t == qt) {
                const int rowloc = w * 16 + quad * 4;
#pragma unroll
                for (int ct = 0; ct < 4; ++ct)
#pragma unroll
                    for (int r = 0; r < 4; ++r)
                        if (ct * 16 + l16 > rowloc + r) S[ct][r] = -1e30f;
            }

            // ---- online softmax, batched reduction trees (r8, kept) ----
            float c0[4];
#pragma unroll
            for (int r = 0; r < 4; ++r)
                c0[r] = fmaxf(fmaxf(S[0][r], S[1][r]), fmaxf(S[2][r], S[3][r]));
#pragma unroll
            for (int st = 1; st <= 8; st <<= 1)
#pragma unroll
                for (int r = 0; r < 4; ++r)
                    c0[r] = fmaxf(c0[r], __shfl_xor(c0[r], st));
            float alpha[4], mh[4], rs[4];
#pragma unroll
            for (int r = 0; r < 4; ++r) {
                float mnew = fmaxf(m_r[r], c0[r]);
                alpha[r] = exp2f((m_r[r] - mnew) * k2);
                m_r[r] = mnew;
                mh[r] = mnew * k2;
                rs[r] = 0.0f;
            }
#pragma unroll
            for (int r = 0; r < 4; ++r) {
                const int prow = quad * 4 + r;
                const int pkey = (prow >> 2) ^ ((prow & 3) << 1);
#pragma unroll
                for (int ct = 0; ct < 4; ++ct) {
                    float p = exp2f(S[ct][r] * k2 - mh[r]);
                    rs[r] += p;
                    int chunk = ct * 2 + (l16 >> 3);
                    union { float f; unsigned u; } pu; pu.f = p;
                    Ps[w][prow * 64 + (chunk ^ pkey) * 8 + (l16 & 7)] =
                        (unsigned short)((pu.u + 0x8000u) >> 16);
                }
            }
#pragma unroll
            for (int st = 1; st <= 8; st <<= 1)
#pragma unroll
                for (int r = 0; r < 4; ++r)
                    rs[r] += __shfl_xor(rs[r], st);
#pragma unroll
            for (int r = 0; r < 4; ++r) {
                l_r[r] = l_r[r] * alpha[r] + rs[r];
#pragma unroll
                for (int ot = 0; ot < 8; ++ot) Oacc[ot][r] *= alpha[r];
            }

            // ---- O += P @ V ----
            {
                const int pkeyr = (l16 >> 2) ^ ((l16 & 3) << 1);
                short8 pf0 = *(const short8*)&Ps[w][l16 * 64 + (quad ^ pkeyr) * 8];
                short8 pf1 = *(const short8*)&Ps[w][l16 * 64 + ((4 + quad) ^ pkeyr) * 8];
#pragma unroll
                for (int ot = 0; ot < 8; ++ot) {
                    const int d = ot * 16 + l16;
                    const int vkey = (l16 + ot) & 7;    // (d + (d>>4)) & 7
                    short8 v0 = *(const short8*)&Vb[d * 32 + (quad ^ vkey) * 4];
                    Oacc[ot] = __builtin_amdgcn_mfma_f32_16x16x32_bf16(pf0, v0, Oacc[ot], 0, 0, 0);
                    short8 v1 = *(const short8*)&Vb[d * 32 + ((4 + quad) ^ vkey) * 4];
                    Oacc[ot] = __builtin_amdgcn_mfma_f32_16x16x32_bf16(pf1, v1, Oacc[ot], 0, 0, 0);
                }
            }
            // no tail barrier: next iteration writes the other buffer
        }

        // ---- epilogue: bf16 store to [B*S, 2048] ----
        float inv[4];
#pragma unroll
        for (int r = 0; r < 4; ++r) inv[r] = 1.0f / l_r[r];
        const int orow0 = q0 + w * 16 + quad * 4;
        unsigned short* ob = o + (size_t)(b * SS + orow0) * 2048 + h * 128 + l16;
#pragma unroll
        for (int r = 0; r < 4; ++r)
#pragma unroll
            for (int ot = 0; ot < 8; ++ot)
                ob[(size_t)r * 2048 + ot * 16] = (unsigned short)f2bf1(Oacc[ot][r] * inv[r]);

        __syncthreads();   // protect LDS buffers across pass boundary
    }
}

// ---------------------------------------------------------------------------
extern "C" void kernel_launch(void* const* d_in, const int* in_sizes, int n_in,
                              void* d_out, int out_size, void* d_ws, size_t ws_size,
                              hipStream_t stream)
{
    const float* x  = (const float*)d_in[0];
    const float* Wq = (const float*)d_in[1];
    const float* bq = (const float*)d_in[2];
    const float* Wk = (const float*)d_in[3];
    const float* bk = (const float*)d_in[4];
    const float* Wv = (const float*)d_in[5];
    const float* bv = (const float*)d_in[6];
    const float* Wo = (const float*)d_in[7];
    float* out = (float*)d_out;

    const int M = BB * SS;  // 4096
    char* wsb = (char*)d_ws;
    unsigned short* xb   = (unsigned short*)wsb;  wsb += (size_t)M * EE * 2;        // 16.8 MB
    unsigned short* wqkv = (unsigned short*)wsb;  wsb += (size_t)3072 * EE * 2;     // 12.6 MB
    unsigned short* wob  = (unsigned short*)wsb;  wsb += (size_t)EE * EE * 2;       //  8.4 MB
    unsigned short* qkvb = (unsigned short*)wsb;  wsb += (size_t)M * 3072 * 2;      // 25.2 MB
    unsigned short* abb  = (unsigned short*)wsb;  wsb += (size_t)M * 2048 * 2;      // 16.8 MB
    float* bqkv = (float*)wsb;                    wsb += 4096 * 4;                  // 16 KB (2560 used)
    float* rtab = (float*)wsb;                    // 1 MB: cos[2048*64] | sin[2048*64]

    // one fused conversion launch (x, Wq, Wk, Wv, Wo, biases, rope table)
    cvt_all_kernel<<<18947, 256, 0, stream>>>(x, Wq, Wk, Wv, Wo, bq, bk, bv,
                                              xb, wqkv, wob, bqkv, rtab);

    // fused QKV projection: [M,3072] = xb @ wqkv^T + bqkv (bf16 out)
    gemm_mfma_kernel<true><<<dim3(3072 / 128, M / 128), 256, 0, stream>>>(
        xb, wqkv, bqkv, qkvb, M, 3072, EE);

    // RoPE on q and k heads, table-based, one block per row
    rope_kernel<<<M, 256, 0, stream>>>(qkvb, rtab, rtab + 131072);

    // flash attention -> abb (bf16)
    attn_mfma_kernel<<<dim3(16, HH, BB), 256, 0, stream>>>(qkvb, abb);

    // output projection: out = abb @ wob^T (fp32 out)
    gemm_mfma_kernel<false><<<dim3(EE / 128, M / 128), 256, 0, stream>>>(
        abb, wob, nullptr, out, M, EE, 2048);
}

// Round 12
// 340.726 us; speedup vs baseline: 1.0335x; 1.0335x over previous
//
#include <hip/hip_runtime.h>
#include <hip/hip_bf16.h>
#include <math.h>

// Problem constants (QwenAttention: B=2,S=2048,E=2048,H=16,KV=4,D=128)
#define BB 2
#define SS 2048
#define EE 2048
#define HH 16
#define KVH 4
#define DD 128
#define QTILES 32   // S / 64

typedef short short8 __attribute__((ext_vector_type(8)));
typedef float f32x4 __attribute__((ext_vector_type(4)));

__device__ __forceinline__ unsigned int f2bf1(float x) {
    union { float f; unsigned int u; } v; v.f = x;
    return (v.u + 0x7FFFu + ((v.u >> 16) & 1u)) >> 16;  // RNE bf16
}
__device__ __forceinline__ unsigned int packbf(float a, float b) {
    return f2bf1(a) | (f2bf1(b) << 16);
}
// async global->LDS, 16B per lane; LDS dest = wave-uniform base + lane*16
__device__ __forceinline__ void gl_lds16(const void* g, void* l) {
    __builtin_amdgcn_global_load_lds(
        (const __attribute__((address_space(1))) unsigned int*)g,
        (__attribute__((address_space(3))) unsigned int*)l,
        16, 0, 0);
}

// ---------------------------------------------------------------------------
// Fused fp32->bf16 conversion of all inputs + bias concat + RoPE cos/sin
// table, one launch. Segments in float4 units: x | Wq | Wk | Wv | Wo |
// biases(fp32) | rope table (cos[2048][64], sin[2048][64] f32).
// ---------------------------------------------------------------------------
__global__ __launch_bounds__(256) void cvt_all_kernel(
    const float* __restrict__ x,  const float* __restrict__ Wq,
    const float* __restrict__ Wk, const float* __restrict__ Wv,
    const float* __restrict__ Wo, const float* __restrict__ bq,
    const float* __restrict__ bk, const float* __restrict__ bv,
    unsigned short* __restrict__ xb, unsigned short* __restrict__ wqkv,
    unsigned short* __restrict__ wob, float* __restrict__ bqkv,
    float* __restrict__ rtab)
{
    long id = (long)blockIdx.x * 256 + threadIdx.x;
    const float* src; unsigned short* dst; long j;
    if (id < 2097152)      { j = id;           src = x;  dst = xb; }
    else if (id < 3145728) { j = id - 2097152; src = Wq; dst = wqkv; }
    else if (id < 3407872) { j = id - 3145728; src = Wk; dst = wqkv + 4194304; }
    else if (id < 3670016) { j = id - 3407872; src = Wv; dst = wqkv + 5242880; }
    else if (id < 4718592) { j = id - 3670016; src = Wo; dst = wob; }
    else if (id < 4719360) {
        long c = (id - 4718592) * 4;
#pragma unroll
        for (int e = 0; e < 4; ++e) {
            long cc = c + e;
            bqkv[cc] = (cc < 2048) ? bq[cc] : (cc < 2560 ? bk[cc - 2048] : bv[cc - 2560]);
        }
        return;
    } else if (id < 4850432) {
        // rope table: one sincos per (s, d) entry
        long e = id - 4719360;            // 0 .. 131071
        int sg = (int)(e >> 6);           // position 0..2047
        int dg = (int)(e & 63);           // freq index 0..63
        float inv_freq = expf(-(float)dg * (logf(10000.0f) / 64.0f));
        float fr = (float)sg * inv_freq;
        rtab[e]          = cosf(fr);
        rtab[131072 + e] = sinf(fr);
        return;
    } else return;
    float4 f = ((const float4*)src)[j];
    ((uint2*)dst)[j] = make_uint2(packbf(f.x, f.y), packbf(f.z, f.w));
}

// ---------------------------------------------------------------------------
// bf16 MFMA GEMM: C[M,N] = A[M,K] @ W[N,K]^T + bias[N]
// 128x128 tile, BK=64, 256 threads = 4 waves (2x2), 4x4 MFMA tiles per wave.
// r9 config (best measured): BK=64 + XOR-swizzled LDS (pre-swizzled global
// src col ((lane&7)^(lane>>3))*8, read chunk' = chunk ^ (row&7)), SINGLE
// buffer, 2 barriers/step. r10 lesson: explicit LDS dbuf regressed (-10us:
// 64KB LDS halves blocks/CU 4->2; lost TLP > overlapped staging; confirms
// m99/m100). This structure is at its ceiling -- do not re-pipeline.
// (r7 lesson: keep the epilogue simple -- no fused rope.)
// ---------------------------------------------------------------------------
template <bool OUT_BF16>
__global__ __launch_bounds__(256) void gemm_mfma_kernel(
    const unsigned short* __restrict__ A, const unsigned short* __restrict__ W,
    const float* __restrict__ bias, void* __restrict__ Cout,
    int M, int N, int K)
{
    __shared__ unsigned short As[128 * 64];
    __shared__ unsigned short Bs[128 * 64];

    const int tid  = threadIdx.x;
    const int w    = tid >> 6;
    const int lane = tid & 63;
    const int quad = lane >> 4;
    const int l16  = lane & 15;
    const int wr   = w >> 1, wc = w & 1;
    const int m0 = blockIdx.y * 128, n0 = blockIdx.x * 128;

    f32x4 acc[4][4];
#pragma unroll
    for (int i = 0; i < 4; ++i)
#pragma unroll
        for (int j = 0; j < 4; ++j) acc[i][j] = (f32x4){0.f, 0.f, 0.f, 0.f};

    // staging map: dest LDS row (within 32-row call-chunk) = w*8 + (lane>>3),
    // dest chunk = lane&7; source col pre-swizzled so LDS logical layout is
    // row-major with chunk' = chunk ^ (row&7); row&7 == lane>>3.
    const int scol = ((lane & 7) ^ (lane >> 3)) * 8;
    const unsigned short* Ag = A + (size_t)(m0 + w * 8 + (lane >> 3)) * K + scol;
    const unsigned short* Wg = W + (size_t)(n0 + w * 8 + (lane >> 3)) * K + scol;
    unsigned short* AsB = &As[(w * 8) * 64];
    unsigned short* BsB = &Bs[(w * 8) * 64];

    const int rkey = (l16 & 7) * 8;   // read-side XOR key (in shorts)

    for (int k0 = 0; k0 < K; k0 += 64) {
#pragma unroll
        for (int c = 0; c < 4; ++c) {
            gl_lds16(Ag + k0 + (size_t)(32 * c) * K, AsB + 32 * c * 64);
            gl_lds16(Wg + k0 + (size_t)(32 * c) * K, BsB + 32 * c * 64);
        }
        __syncthreads();

#pragma unroll
        for (int ks = 0; ks < 2; ++ks) {
            short8 a_f[4], b_f[4];
#pragma unroll
            for (int i = 0; i < 4; ++i)
                a_f[i] = *(const short8*)&As[(wr * 64 + i * 16 + l16) * 64 + (((ks * 4 + quad) * 8) ^ rkey)];
#pragma unroll
            for (int j = 0; j < 4; ++j)
                b_f[j] = *(const short8*)&Bs[(wc * 64 + j * 16 + l16) * 64 + (((ks * 4 + quad) * 8) ^ rkey)];
#pragma unroll
            for (int i = 0; i < 4; ++i)
#pragma unroll
                for (int j = 0; j < 4; ++j)
                    acc[i][j] = __builtin_amdgcn_mfma_f32_16x16x32_bf16(a_f[i], b_f[j], acc[i][j], 0, 0, 0);
        }
        __syncthreads();
    }

    float bj[4];
#pragma unroll
    for (int j = 0; j < 4; ++j)
        bj[j] = bias ? bias[n0 + wc * 64 + j * 16 + l16] : 0.0f;
#pragma unroll
    for (int i = 0; i < 4; ++i) {
#pragma unroll
        for (int r = 0; r < 4; ++r) {
            size_t row = m0 + wr * 64 + i * 16 + quad * 4 + r;
#pragma unroll
            for (int j = 0; j < 4; ++j) {
                size_t col = n0 + wc * 64 + j * 16 + l16;
                float val = acc[i][j][r] + bj[j];
                if (OUT_BF16)
                    ((unsigned short*)Cout)[row * N + col] = (unsigned short)f2bf1(val);
                else
                    ((float*)Cout)[row * N + col] = val;
            }
        }
    }
}

// ---------------------------------------------------------------------------
// RoPE on K heads only (q-rope is fused into attn's Q-frag load -- each Q
// row is loaded by exactly one attn block-pass, so rope-on-load duplicates
// nothing; K is read by 64 blocks and must stay pre-roped here).
// One block per row, 256 threads: hh = tid>>6 (4 kv heads), d = tid&63.
// Touches 8.4 MB (vs 42 MB when q was included).
// ---------------------------------------------------------------------------
__global__ __launch_bounds__(256) void rope_k_kernel(
    unsigned short* __restrict__ qkv,
    const float* __restrict__ ctab, const float* __restrict__ stab)
{
    const int m = blockIdx.x;          // row in [0, B*S)
    const int s = m & (SS - 1);
    const int hh = threadIdx.x >> 6;   // 0..3
    const int d  = threadIdx.x & 63;
    unsigned short* p = qkv + (size_t)m * 3072 + 2048 + hh * 128;
    float c  = ctab[s * 64 + d];
    float sn = stab[s * 64 + d];
    union { unsigned int u; float f; } x1, x2;
    x1.u = ((unsigned int)p[d]) << 16;
    x2.u = ((unsigned int)p[d + 64]) << 16;
    p[d]      = (unsigned short)f2bf1(x1.f * c - x2.f * sn);
    p[d + 64] = (unsigned short)f2bf1(x2.f * c + x1.f * sn);
}

// ---------------------------------------------------------------------------
// Flash attention, bf16, MFMA 16x16x32, XOR-swizzled LDS (conflict-free),
// double-buffered K/V with register prefetch -> ONE barrier per K-tile.
// 512 blocks, each does TWO q-tiles (jpair, 31-jpair) = uniform 33 KV-units.
// Structure locked by rounds 1/2/4/6/8 (all null or regressed): keep dbuf +
// (256,2); no split-KV, no XCD swizzle, no setprio, no defer-rescale.
// Q-RoPE fused into the Q-frag load: the rope pair (d, d+64) lives in
// qf[ks] / qf[ks+2] of the SAME thread (cols = quad*8 + ks*32), so the
// rotation is 16 in-register fma-pairs per pass, amortized over ~33
// KV-tiles. Same bf16 rounding count as the standalone path.
// qkv: [B*S, 3072] (q: h*128, k: 2048+kv*128, v: 2560+kv*128); o: [B*S, 2048].
// Swizzle keys: K/V chunk' = chunk ^ ((row + (row>>4)) & 7) at 16B-chunk
// granularity; P chunk' = chunk ^ ((row>>2) ^ ((row&3)<<1)).
// ---------------------------------------------------------------------------
__global__ __launch_bounds__(256, 2) void attn_mfma_kernel(
    const unsigned short* __restrict__ qkv, unsigned short* __restrict__ o,
    const float* __restrict__ ctab, const float* __restrict__ stab)
{
    __shared__ unsigned int Ks_u[2][64 * 64];    // 2 x 16 KB
    __shared__ unsigned int Vs_u[2][128 * 32];   // 2 x 16 KB
    __shared__ unsigned short Ps[4][16 * 64];    // 8 KB, per-wave

    const int tid  = threadIdx.x;
    const int w    = tid >> 6;
    const int lane = tid & 63;
    const int quad = lane >> 4;
    const int l16  = lane & 15;
    const int jpair = blockIdx.x;   // 0..15
    const int h     = blockIdx.y;
    const int b     = blockIdx.z;
    const int kv    = h >> 2;       // G = 4

    const float k2 = 0.12752789744920764f;  // (1/sqrt(128)) * log2(e)

    const unsigned short* kbase = qkv + (size_t)b * SS * 3072 + 2048 + kv * 128;
    const unsigned short* vbase = kbase + 512;

    const int kc  = tid & 15;          // K chunk (8 dims)
    const int kp0 = tid >> 4;          // K row base 0..15
    const int vpp = tid >> 3;          // V pos-pair 0..31
    const int vd0 = (tid & 7) * 16;    // V d-segment base

    for (int pass = 0; pass < 2; ++pass) {
        const int qt = pass ? (QTILES - 1 - jpair) : jpair;
        const int q0 = qt * 64;

        // ---- Q A-frags + fused Q-RoPE ----
        short8 qf[4];
        {
            const unsigned short* qp = qkv + (size_t)(b * SS + q0 + w * 16 + l16) * 3072 + h * 128 + quad * 8;
#pragma unroll
            for (int ks = 0; ks < 4; ++ks)
                qf[ks] = *(const short8*)(qp + ks * 32);
            const int s = q0 + w * 16 + l16;
            const float* cr = ctab + s * 64;
            const float* sr = stab + s * 64;
#pragma unroll
            for (int ks = 0; ks < 2; ++ks) {
#pragma unroll
                for (int j = 0; j < 8; ++j) {
                    int d = quad * 8 + ks * 32 + j;     // 0..63
                    float c  = cr[d];
                    float sn = sr[d];
                    union { unsigned int u; float f; } lo, hi;
                    lo.u = ((unsigned int)(unsigned short)qf[ks][j]) << 16;
                    hi.u = ((unsigned int)(unsigned short)qf[ks + 2][j]) << 16;
                    qf[ks][j]     = (short)(unsigned short)f2bf1(lo.f * c - hi.f * sn);
                    qf[ks + 2][j] = (short)(unsigned short)f2bf1(hi.f * c + lo.f * sn);
                }
            }
        }

        // ---- prefetch tile 0 into regs ----
        uint4 kpre[4], vpa[2], vpb[2];
        {
            const unsigned short* kg = kbase + (size_t)kp0 * 3072 + kc * 8;
#pragma unroll
            for (int rr = 0; rr < 4; ++rr)
                kpre[rr] = *(const uint4*)(kg + (size_t)rr * 16 * 3072);
            const unsigned short* vg = vbase + (size_t)(2 * vpp) * 3072 + vd0;
            vpa[0] = *(const uint4*)(vg);
            vpa[1] = *(const uint4*)(vg + 8);
            vpb[0] = *(const uint4*)(vg + 3072);
            vpb[1] = *(const uint4*)(vg + 3072 + 8);
        }

        float m_r[4], l_r[4];
        f32x4 Oacc[8];
#pragma unroll
        for (int r = 0; r < 4; ++r) { m_r[r] = -1e30f; l_r[r] = 0.0f; }
#pragma unroll
        for (int ot = 0; ot < 8; ++ot) Oacc[ot] = (f32x4){0.f, 0.f, 0.f, 0.f};

        for (int t = 0; t <= qt; ++t) {
            const int buf = t & 1;
            unsigned int* Kb = Ks_u[buf];
            unsigned int* Vb = Vs_u[buf];

            // ---- staged regs -> LDS (swizzled, conflict-free) ----
#pragma unroll
            for (int rr = 0; rr < 4; ++rr) {
                int pos = kp0 + rr * 16;
                int key = (kp0 + rr) & 7;           // (pos + (pos>>4)) & 7
                *(uint4*)&Kb[pos * 64 + (kc ^ key) * 4] = kpre[rr];
            }
            {
                const unsigned int* pa = (const unsigned int*)vpa;
                const unsigned int* pb = (const unsigned int*)vpb;
#pragma unroll
                for (int j = 0; j < 8; ++j) {
                    unsigned lo = __builtin_amdgcn_perm(pb[j], pa[j], 0x05040100);
                    unsigned hi = __builtin_amdgcn_perm(pb[j], pa[j], 0x07060302);
                    int d0 = vd0 + 2 * j;
                    int g  = d0 >> 4;               // same for d0 and d0+1
                    int k0 = (d0 + g) & 7;
                    int k1 = (d0 + 1 + g) & 7;
                    Vb[d0 * 32 + (((vpp >> 2) ^ k0) & 7) * 4 + (vpp & 3)] = lo;
                    Vb[(d0 + 1) * 32 + (((vpp >> 2) ^ k1) & 7) * 4 + (vpp & 3)] = hi;
                }
            }

            // ---- prefetch tile t+1 (latency hidden under compute) ----
            if (t < qt) {
                const unsigned short* kg = kbase + (size_t)((t + 1) * 64 + kp0) * 3072 + kc * 8;
#pragma unroll
                for (int rr = 0; rr < 4; ++rr)
                    kpre[rr] = *(const uint4*)(kg + (size_t)rr * 16 * 3072);
                const unsigned short* vg = vbase + (size_t)((t + 1) * 64 + 2 * vpp) * 3072 + vd0;
                vpa[0] = *(const uint4*)(vg);
                vpa[1] = *(const uint4*)(vg + 8);
                vpb[0] = *(const uint4*)(vg + 3072);
                vpb[1] = *(const uint4*)(vg + 3072 + 8);
            }
            __syncthreads();

            // ---- S = Q @ K^T (16x64 per wave), raw scores ----
            f32x4 S[4];
#pragma unroll
            for (int ct = 0; ct < 4; ++ct) {
                f32x4 s = (f32x4){0.f, 0.f, 0.f, 0.f};
                const int row = ct * 16 + l16;
                const int key = (l16 + ct) & 7;     // (pos + (pos>>4)) & 7
#pragma unroll
                for (int ks = 0; ks < 4; ++ks) {
                    short8 kf = *(const short8*)&Kb[row * 64 + ((ks * 4 + quad) ^ key) * 4];
                    s = __builtin_amdgcn_mfma_f32_16x16x32_bf16(qf[ks], kf, s, 0, 0, 0);
                }
                S[ct] = s;
            }

            // ---- causal mask (diagonal tile only) ----
            if (t == qt) {
                const int rowloc = w * 16 + quad * 4;
#pragma unroll
                for (int ct = 0; ct < 4; ++ct)
#pragma unroll
                    for (int r = 0; r < 4; ++r)
                        if (ct * 16 + l16 > rowloc + r) S[ct][r] = -1e30f;
            }

            // ---- online softmax, batched reduction trees (r8, kept) ----
            float c0[4];
#pragma unroll
            for (int r = 0; r < 4; ++r)
                c0[r] = fmaxf(fmaxf(S[0][r], S[1][r]), fmaxf(S[2][r], S[3][r]));
#pragma unroll
            for (int st = 1; st <= 8; st <<= 1)
#pragma unroll
                for (int r = 0; r < 4; ++r)
                    c0[r] = fmaxf(c0[r], __shfl_xor(c0[r], st));
            float alpha[4], mh[4], rs[4];
#pragma unroll
            for (int r = 0; r < 4; ++r) {
                float mnew = fmaxf(m_r[r], c0[r]);
                alpha[r] = exp2f((m_r[r] - mnew) * k2);
                m_r[r] = mnew;
                mh[r] = mnew * k2;
                rs[r] = 0.0f;
            }
#pragma unroll
            for (int r = 0; r < 4; ++r) {
                const int prow = quad * 4 + r;
                const int pkey = (prow >> 2) ^ ((prow & 3) << 1);
#pragma unroll
                for (int ct = 0; ct < 4; ++ct) {
                    float p = exp2f(S[ct][r] * k2 - mh[r]);
                    rs[r] += p;
                    int chunk = ct * 2 + (l16 >> 3);
                    union { float f; unsigned u; } pu; pu.f = p;
                    Ps[w][prow * 64 + (chunk ^ pkey) * 8 + (l16 & 7)] =
                        (unsigned short)((pu.u + 0x8000u) >> 16);
                }
            }
#pragma unroll
            for (int st = 1; st <= 8; st <<= 1)
#pragma unroll
                for (int r = 0; r < 4; ++r)
                    rs[r] += __shfl_xor(rs[r], st);
#pragma unroll
            for (int r = 0; r < 4; ++r) {
                l_r[r] = l_r[r] * alpha[r] + rs[r];
#pragma unroll
                for (int ot = 0; ot < 8; ++ot) Oacc[ot][r] *= alpha[r];
            }

            // ---- O += P @ V ----
            {
                const int pkeyr = (l16 >> 2) ^ ((l16 & 3) << 1);
                short8 pf0 = *(const short8*)&Ps[w][l16 * 64 + (quad ^ pkeyr) * 8];
                short8 pf1 = *(const short8*)&Ps[w][l16 * 64 + ((4 + quad) ^ pkeyr) * 8];
#pragma unroll
                for (int ot = 0; ot < 8; ++ot) {
                    const int d = ot * 16 + l16;
                    const int vkey = (l16 + ot) & 7;    // (d + (d>>4)) & 7
                    short8 v0 = *(const short8*)&Vb[d * 32 + (quad ^ vkey) * 4];
                    Oacc[ot] = __builtin_amdgcn_mfma_f32_16x16x32_bf16(pf0, v0, Oacc[ot], 0, 0, 0);
                    short8 v1 = *(const short8*)&Vb[d * 32 + ((4 + quad) ^ vkey) * 4];
                    Oacc[ot] = __builtin_amdgcn_mfma_f32_16x16x32_bf16(pf1, v1, Oacc[ot], 0, 0, 0);
                }
            }
            // no tail barrier: next iteration writes the other buffer
        }

        // ---- epilogue: bf16 store to [B*S, 2048] ----
        float inv[4];
#pragma unroll
        for (int r = 0; r < 4; ++r) inv[r] = 1.0f / l_r[r];
        const int orow0 = q0 + w * 16 + quad * 4;
        unsigned short* ob = o + (size_t)(b * SS + orow0) * 2048 + h * 128 + l16;
#pragma unroll
        for (int r = 0; r < 4; ++r)
#pragma unroll
            for (int ot = 0; ot < 8; ++ot)
                ob[(size_t)r * 2048 + ot * 16] = (unsigned short)f2bf1(Oacc[ot][r] * inv[r]);

        __syncthreads();   // protect LDS buffers across pass boundary
    }
}

// ---------------------------------------------------------------------------
extern "C" void kernel_launch(void* const* d_in, const int* in_sizes, int n_in,
                              void* d_out, int out_size, void* d_ws, size_t ws_size,
                              hipStream_t stream)
{
    const float* x  = (const float*)d_in[0];
    const float* Wq = (const float*)d_in[1];
    const float* bq = (const float*)d_in[2];
    const float* Wk = (const float*)d_in[3];
    const float* bk = (const float*)d_in[4];
    const float* Wv = (const float*)d_in[5];
    const float* bv = (const float*)d_in[6];
    const float* Wo = (const float*)d_in[7];
    float* out = (float*)d_out;

    const int M = BB * SS;  // 4096
    char* wsb = (char*)d_ws;
    unsigned short* xb   = (unsigned short*)wsb;  wsb += (size_t)M * EE * 2;        // 16.8 MB
    unsigned short* wqkv = (unsigned short*)wsb;  wsb += (size_t)3072 * EE * 2;     // 12.6 MB
    unsigned short* wob  = (unsigned short*)wsb;  wsb += (size_t)EE * EE * 2;       //  8.4 MB
    unsigned short* qkvb = (unsigned short*)wsb;  wsb += (size_t)M * 3072 * 2;      // 25.2 MB
    unsigned short* abb  = (unsigned short*)wsb;  wsb += (size_t)M * 2048 * 2;      // 16.8 MB
    float* bqkv = (float*)wsb;                    wsb += 4096 * 4;                  // 16 KB (2560 used)
    float* rtab = (float*)wsb;                    // 1 MB: cos[2048*64] | sin[2048*64]

    // one fused conversion launch (x, Wq, Wk, Wv, Wo, biases, rope table)
    cvt_all_kernel<<<18947, 256, 0, stream>>>(x, Wq, Wk, Wv, Wo, bq, bk, bv,
                                              xb, wqkv, wob, bqkv, rtab);

    // fused QKV projection: [M,3072] = xb @ wqkv^T + bqkv (bf16 out)
    gemm_mfma_kernel<true><<<dim3(3072 / 128, M / 128), 256, 0, stream>>>(
        xb, wqkv, bqkv, qkvb, M, 3072, EE);

    // RoPE on K heads only (Q-rope fused into attention)
    rope_k_kernel<<<M, 256, 0, stream>>>(qkvb, rtab, rtab + 131072);

    // flash attention -> abb (bf16); Q-rope applied in-register
    attn_mfma_kernel<<<dim3(16, HH, BB), 256, 0, stream>>>(
        qkvb, abb, rtab, rtab + 131072);

    // output projection: out = abb @ wob^T (fp32 out)
    gemm_mfma_kernel<false><<<dim3(EE / 128, M / 128), 256, 0, stream>>>(
        abb, wob, nullptr, out, M, EE, 2048);
}